// Round 7
// baseline (775723.145 us; speedup 1.0000x reference)
//
#include <hip/hip_runtime.h>
#include <hip/hip_cooperative_groups.h>
#include <math.h>

namespace cg = cooperative_groups;

#define RR 512
#define TT 262144
#define OSTR 513
#define JSQ 17
#define NBLK 8

// ---- fallback scratch carved out of d_out (float offsets) ----
// f64 prelude scratch at rows 8192..~10240, overwritten by k_main's stores later.
static constexpr size_t SCR_OFF = (size_t)8192 * OSTR;       // 8B-aligned
// fallback state double-buffer: first 1024 floats of the last 4 rows (+1 for sr).
static constexpr size_t GS_OFF  = (size_t)(TT - 4) * OSTR;   // 8B-aligned
static constexpr size_t SR_OFFN = GS_OFF + 1024;             // sr scalar

// ---------------- prelude: spectral radius via f64 repeated squaring ----------------

__global__ void k_copy(const float* __restrict__ W, double* __restrict__ A) {
  int g = blockIdx.x * 256 + threadIdx.x;
  A[g] = (double)W[g];
}

__global__ void k_frob_part(const double* __restrict__ M, double* __restrict__ part) {
  __shared__ double red[256];
  int t = threadIdx.x;
  int g = blockIdx.x * 256 + t;
  double s = 0.0;
  for (int i = g; i < RR * RR; i += 65536) { double v = M[i]; s = fma(v, v, s); }
  red[t] = s; __syncthreads();
  for (int o = 128; o > 0; o >>= 1) { if (t < o) red[t] += red[t + o]; __syncthreads(); }
  if (t == 0) part[blockIdx.x] = red[0];
}

__global__ void k_frob_fin(const double* __restrict__ part, double* __restrict__ c2slot) {
  __shared__ double red[256];
  int t = threadIdx.x;
  red[t] = part[t]; __syncthreads();
  for (int o = 128; o > 0; o >>= 1) { if (t < o) red[t] += red[t + o]; __syncthreads(); }
  if (t == 0) *c2slot = red[0];
}

// Out = (M @ M) / c2   (i.e. (M/c)^2 with c = frob norm, c2 = c^2)
__global__ void k_matsq(const double* __restrict__ M, double* __restrict__ Out,
                        const double* __restrict__ c2ptr) {
  __shared__ double As[16][17];
  __shared__ double Bs[16][17];
  int tx = threadIdx.x & 15, ty = threadIdx.x >> 4;
  int bx = blockIdx.x & 31, by = blockIdx.x >> 5;
  int row = by * 16 + ty, col = bx * 16 + tx;
  double acc = 0.0;
  for (int bk = 0; bk < 32; ++bk) {
    As[ty][tx] = M[row * RR + bk * 16 + tx];
    Bs[ty][tx] = M[(bk * 16 + ty) * RR + col];
    __syncthreads();
#pragma unroll
    for (int k = 0; k < 16; ++k) acc = fma(As[ty][k], Bs[k][tx], acc);
    __syncthreads();
  }
  Out[row * RR + col] = acc * (1.0 / *c2ptr);
}

__device__ __forceinline__ double blk_red512d(double v, double* red, int t) {
  red[t] = v; __syncthreads();
  for (int o = 256; o > 0; o >>= 1) { if (t < o) red[t] += red[t + o]; __syncthreads(); }
  double r = red[0]; __syncthreads();
  return r;
}

// Dominant modulus of the squared chain via 2-D projected 2x2 eigenproblem
// (handles real AND complex-pair dominant eigenvalues); undo normalization in f64.
__global__ void k_power(const double* __restrict__ M, const double* __restrict__ c2,
                        float* __restrict__ srout) {
  __shared__ double v[512], q1[512], q2[512], red[512];
  const int t = threadIdx.x;
  unsigned h = (unsigned)t * 2654435761u;
  h ^= h >> 16; h *= 2246822519u; h ^= h >> 13;
  v[t] = (double)((h >> 8) & 0xFFFFFF) * (1.0 / 16777216.0) - 0.5;
  __syncthreads();
  for (int it = 0; it < 3; ++it) {
    double acc = 0.0;
    const double* row = M + (size_t)t * RR;
    for (int k = 0; k < RR; ++k) acc = fma(row[k], v[k], acc);
    __syncthreads();
    double n2 = blk_red512d(acc * acc, red, t);
    double inv = 1.0 / sqrt(n2);
    if (it == 1) q1[t] = acc * inv;
    v[t] = acc * inv;
    __syncthreads();
  }
  double g  = blk_red512d(q1[t] * v[t], red, t);
  double q2r = v[t] - g * q1[t];
  double n2 = blk_red512d(q2r * q2r, red, t);
  q2[t] = q2r / sqrt(n2);
  __syncthreads();
  double b1 = 0.0;
  { const double* row = M + (size_t)t * RR;
    for (int k = 0; k < RR; ++k) b1 = fma(row[k], q1[k], b1); }
  double a  = blk_red512d(q1[t] * b1, red, t);
  double cc = blk_red512d(q2[t] * b1, red, t);
  double b2 = 0.0;
  { const double* row = M + (size_t)t * RR;
    for (int k = 0; k < RR; ++k) b2 = fma(row[k], q2[k], b2); }
  double b  = blk_red512d(q1[t] * b2, red, t);
  double dd = blk_red512d(q2[t] * b2, red, t);
  if (t == 0) {
    double tr  = a + dd;
    double det = a * dd - b * cc;
    double disc = tr * tr - 4.0 * det;
    double rho;
    if (disc >= 0.0) { double s = sqrt(disc); rho = 0.5 * (fabs(tr) + s); }
    else             { rho = sqrt(det); }   // complex pair: |lambda|^2 = det
    double L = ldexp(log(rho), -JSQ);
    for (int j = 0; j < JSQ; ++j) L += ldexp(0.5 * log(c2[j]), -j);
    srout[0] = (float)exp(L);
  }
}

// col 512 = X (INPUT_SCALING = 1.0), row 0 = zeros.
__global__ void k_fill(const float* __restrict__ X, float* __restrict__ out) {
  int g = blockIdx.x * 256 + threadIdx.x;
  out[(size_t)g * OSTR + RR] = X[g];
  if (g < RR) out[g] = 0.f;
}

// ---------------- main recurrence: cooperative, NBLK blocks x 512 threads ----------------
// Block b owns rows [64b, 64b+64). Thread: rl = tid>>3 (local row), kc = tid&7
// (64-col chunk); 64 weights in VGPRs (~100 VGPR total -> 2 waves/SIMD).
// Per step: stage prev state coalesced into padded LDS (one wave-instruction
// per wave; conflict-free ds_read_b128 after), 64 FMAs, 3-step shfl_xor
// width-8 reduce, writers (kc==0) do tanh + state store + output store, then
// grid.sync() (cross-XCD visibility + ordering). No custom protocol, no
// spins, no atomics in the loop; every thread reaches every barrier
// unconditionally (deadlock-free by construction).
// LDS pad: element g lives at g + (g>>6)*4 -> chunk kc base = 68*kc floats
// (272B, 16B-aligned); the 8 unique float4s per instr start at banks 4*kc
// -> spread across all 32 banks; 8-way same-address reads broadcast free.
// NOTE: out/gs may alias (fallback mode) -> deliberately NOT __restrict__.
__global__ __launch_bounds__(512, 2)
void k_main(const float* __restrict__ Wres, const float* __restrict__ X,
            const float* __restrict__ Win, float* out,
            float* gs, const float* srp, int ovl) {
  cg::grid_group grid = cg::this_grid();
  const int tid = threadIdx.x;
  const int blk = blockIdx.x;            // 0..NBLK-1
  const int kc  = tid & 7;               // 64-col chunk
  const int rl  = tid >> 3;              // local row 0..63
  const int row = (blk << 6) + rl;       // global row this thread's writer owns
  const bool writer = (kc == 0);

  __shared__ __align__(16) float lds_s[8 * 68];   // padded staged state
  __shared__ float lds_x[2048];

  const float sr = *srp;
  const float rinv = 1.0f / sr;

  float w[64];
  {
    const float4* wp = reinterpret_cast<const float4*>(Wres + ((size_t)row << 9) + (kc << 6));
#pragma unroll
    for (int j4 = 0; j4 < 16; ++j4) {
      float4 v = wp[j4];
      w[4 * j4 + 0] = v.x * rinv;
      w[4 * j4 + 1] = v.y * rinv;
      w[4 * j4 + 2] = v.z * rinv;
      w[4 * j4 + 3] = v.w * rinv;
    }
  }
  const float win_r = Win[row];

#pragma unroll
  for (int i = 0; i < 4; ++i) lds_x[tid + 512 * i] = X[tid + 512 * i];
  if (writer) gs[row] = 0.f;            // state buffer 0 = s0 = 0
  __syncthreads();
  grid.sync();                          // init visible everywhere

  const int lds_wr = tid + ((tid >> 6) << 2);   // padded stage-write index
  const float* lds_rd = &lds_s[kc * 68];        // padded chunk base (16B-aligned)
  float* const gs0 = gs;                        // slot for even t-1
  float* const gs1 = gs + 512;                  // slot for odd  t-1

  float z0 = 0.f, z1 = 0.f, z2 = 0.f, z3 = 0.f;

#pragma clang loop unroll(disable)
  for (int t = 1; t < TT; ++t) {
    // stage prev state FIRST (global-load latency off the critical path as
    // much as possible); prev grid.sync -> visible, and its block-level
    // barrier also makes overwriting lds_s/lds_x safe.
    const float sv = ((t & 1) ? gs0 : gs1)[tid];
    if ((t & 2047) == 0) {              // refill X window [t, t+2048)
#pragma unroll
      for (int i = 0; i < 4; ++i) lds_x[tid + 512 * i] = X[t + tid + 512 * i];
    }
    lds_s[lds_wr] = sv;
    __syncthreads();

    float acc = 0.f;
#pragma unroll
    for (int j4 = 0; j4 < 16; ++j4) {
      float4 s4 = reinterpret_cast<const float4*>(lds_rd)[j4];
      acc = fmaf(w[4 * j4 + 0], s4.x, acc);
      acc = fmaf(w[4 * j4 + 1], s4.y, acc);
      acc = fmaf(w[4 * j4 + 2], s4.z, acc);
      acc = fmaf(w[4 * j4 + 3], s4.w, acc);
    }
    acc += __shfl_xor(acc, 1, 8);
    acc += __shfl_xor(acc, 2, 8);
    acc += __shfl_xor(acc, 4, 8);

    if (writer) {
      float z = tanhf(fmaf(lds_x[t & 2047], win_r, acc));
      ((t & 1) ? gs1 : gs0)[row] = z;
      if (!ovl || t < TT - 4)  out[(size_t)t * OSTR + row] = z;
      else if (t == TT - 4) z0 = z;   // fallback: rows TT-4..TT-1 alias gs
      else if (t == TT - 3) z1 = z;
      else if (t == TT - 2) z2 = z;
      else                  z3 = z;
    }
    grid.sync();                       // publish s_t; also orders next-iter reads
  }

  if (!ovl) return;   // ws-mode: output already complete

  // The loop's final grid.sync() IS the termination barrier: every block is past
  // all gs reads -> safe to overwrite the aliased region with the real output.
  if (writer) {
    out[(size_t)(TT - 4) * OSTR + row] = z0;
    out[(size_t)(TT - 3) * OSTR + row] = z1;
    out[(size_t)(TT - 2) * OSTR + row] = z2;
    out[(size_t)(TT - 1) * OSTR + row] = z3;
  }
  if (blk == 0 && tid < 4)
    out[(size_t)(TT - 4 + tid) * OSTR + RR] = X[TT - 4 + tid];  // col-512 repair
}

extern "C" void kernel_launch(void* const* d_in, const int* in_sizes, int n_in,
                              void* d_out, int out_size, void* d_ws, size_t ws_size,
                              hipStream_t stream) {
  (void)in_sizes; (void)n_in; (void)out_size;
  const float* W  = (const float*)d_in[0];
  const float* X  = (const float*)d_in[1];
  const float* Wi = (const float*)d_in[2];
  float* o = (float*)d_out;

  double* DA   = (double*)(o + SCR_OFF);
  double* DB   = DA + (size_t)RR * RR;
  double* c2   = DB + (size_t)RR * RR;   // 32 slots
  double* part = c2 + 32;                // 256 partials

  // state double-buffer: prefer d_ws (removes all overlap-with-output hazards)
  float* gs;  float* srp;  int ovl;
  if (d_ws != nullptr && ws_size >= 4104) {
    gs  = (float*)d_ws;                  // 2 x 512 floats
    srp = (float*)((char*)d_ws + 4096);
    ovl = 0;
  } else {
    gs  = o + GS_OFF;
    srp = o + SR_OFFN;
    ovl = 1;
  }

  hipLaunchKernelGGL(k_copy, dim3(1024), dim3(256), 0, stream, W, DA);
  for (int j = 0; j < JSQ; ++j) {
    const double* src = (j & 1) ? (const double*)DB : (const double*)DA;
    double*       dst = (j & 1) ? DA : DB;
    hipLaunchKernelGGL(k_frob_part, dim3(256),  dim3(256), 0, stream, src, part);
    hipLaunchKernelGGL(k_frob_fin,  dim3(1),    dim3(256), 0, stream, part, c2 + j);
    hipLaunchKernelGGL(k_matsq,     dim3(1024), dim3(256), 0, stream, src, dst, c2 + j);
  }
  // JSQ=17: last squaring (j=16, even) wrote DB
  hipLaunchKernelGGL(k_power, dim3(1), dim3(512), 0, stream, DB, c2, srp);
  hipLaunchKernelGGL(k_fill,  dim3(1024), dim3(256), 0, stream, X, o);

  void* args[] = { (void*)&W, (void*)&X, (void*)&Wi, (void*)&o,
                   (void*)&gs, (void*)&srp, (void*)&ovl };
  hipLaunchCooperativeKernel((const void*)k_main, dim3(NBLK), dim3(512),
                             args, 0, stream);
}